// Round 3
// baseline (583.965 us; speedup 1.0000x reference)
//
#include <hip/hip_runtime.h>

#define NN 8192
#define FIN 128
#define FOUT 64
#define NEGINF (-9e15f)
#define LALPHA 0.2f

typedef float f32x4 __attribute__((ext_vector_type(4)));
typedef float f32x2 __attribute__((ext_vector_type(2)));
typedef short short8 __attribute__((ext_vector_type(8)));

__device__ __forceinline__ unsigned short f32_to_bf16(float x) {
  unsigned int u = __float_as_uint(x);
  u = (u + 0x7fffu + ((u >> 16) & 1u)) >> 16;
  return (unsigned short)u;
}
__device__ __forceinline__ float bf16_to_f32(unsigned short b) {
  return __uint_as_float(((unsigned int)b) << 16);
}

// Kernel 1: Wh = h@W (fp32), s1 = Wh@a1, s2 = Wh@a2, Wh pre-swizzled into the
// MFMA B-fragment layout (bf16 hi) so gat_attn's B loads are coalesced dwordx4.
__global__ __launch_bounds__(256) void gat_prep(
    const float* __restrict__ h, const float* __restrict__ W,
    const float* __restrict__ a,
    float* __restrict__ s1g, float* __restrict__ s2g,
    unsigned short* __restrict__ whfh)
{
  __shared__ __align__(16) float Wl[FIN * FOUT];
  __shared__ __align__(16) float hl[16 * FIN];
  const int tid = threadIdx.x;
  const int i0 = blockIdx.x * 16;
  #pragma unroll
  for (int it = 0; it < 8; ++it) {
    int idx = (it * 256 + tid) * 4;
    *(f32x4*)&Wl[idx] = *(const f32x4*)&W[idx];
  }
  #pragma unroll
  for (int it = 0; it < 2; ++it) {
    int idx = (it * 256 + tid) * 4;
    *(f32x4*)&hl[idx] = *(const f32x4*)&h[(size_t)i0 * FIN + idx];
  }
  __syncthreads();
  const int r = tid >> 4;
  const int f0 = (tid & 15) * 4;
  f32x4 acc = {0.f, 0.f, 0.f, 0.f};
  #pragma unroll 8
  for (int k = 0; k < FIN; ++k) {
    float hv = hl[r * FIN + k];
    f32x4 wv = *(const f32x4*)&Wl[k * FOUT + f0];
    acc += hv * wv;
  }
  f32x4 a1v = *(const f32x4*)&a[f0];
  f32x4 a2v = *(const f32x4*)&a[FOUT + f0];
  float p1 = acc.x * a1v.x + acc.y * a1v.y + acc.z * a1v.z + acc.w * a1v.w;
  float p2 = acc.x * a2v.x + acc.y * a2v.y + acc.z * a2v.z + acc.w * a2v.w;
  #pragma unroll
  for (int d = 1; d < 16; d <<= 1) {
    p1 += __shfl_xor(p1, d, 16);
    p2 += __shfl_xor(p2, d, 16);
  }
  const int j = i0 + r;  // row of Wh == K index of PV
  if ((tid & 15) == 0) { s1g[j] = p1; s2g[j] = p2; }
  // B-fragment layout for mfma_f32_16x16x32_bf16:
  // value Wh[k][n] -> frag[(kstep*4 + n/16)*512 + (((k%32)/8)*16 + n%16)*8 + k%8]
  const int kstep = j >> 5;
  const int lhi = (j >> 3) & 3;
  const int ein = j & 7;
  #pragma unroll
  for (int e = 0; e < 4; ++e) {
    int f = f0 + e;
    unsigned short hb = f32_to_bf16(acc[e]);
    int ln = lhi * 16 + (f & 15);
    whfh[(size_t)(kstep * 4 + (f >> 4)) * 512 + ln * 8 + ein] = hb;
  }
}

// Kernel 2: one wave per row. Single pass over adj builds the neighbor bitmask
// (ballot) + masked row-max of s2 (m = lrelu(s1 + max) by monotonicity), then
// the l-pass runs from LDS only. The 1KB bitmask is stashed into the first
// 1KB of this row of the attention output (L3-resident scratch; gat_attn reads
// it before overwriting). m and 1/l go to ws.
__global__ __launch_bounds__(256, 4) void gat_mask(
    const int* __restrict__ adj,
    const float* __restrict__ s1g, const float* __restrict__ s2g,
    float* __restrict__ outa,
    float* __restrict__ mrow, float* __restrict__ rlrow)
{
  __shared__ __align__(16) float s2l[NN];              // 32 KB
  __shared__ unsigned long long mw[4][128];            // 4 KB
  const int tid = threadIdx.x;
  const int lane = tid & 63;
  const int wv = tid >> 6;
  const int row = blockIdx.x * 4 + wv;
  #pragma unroll
  for (int it = 0; it < 8; ++it) {
    int idx = (it * 256 + tid) * 4;
    *(f32x4*)&s2l[idx] = *(const f32x4*)&s2g[idx];
  }
  __syncthreads();
  const int* __restrict__ ar = adj + (size_t)row * NN;
  float mx = -3.4e38f;
  #pragma unroll 4
  for (int it = 0; it < 128; ++it) {
    int jj = it * 64 + lane;
    int av = __builtin_nontemporal_load(&ar[jj]);
    unsigned long long b = __ballot(av > 0);
    mx = fmaxf(mx, (av > 0) ? s2l[jj] : -3.4e38f);
    if (lane == 0) mw[wv][it] = b;
  }
  #pragma unroll
  for (int d = 1; d < 64; d <<= 1) mx = fmaxf(mx, __shfl_xor(mx, d));
  const float s1v = s1g[row];
  const float z = s1v + mx;
  const float m = (mx <= -3.3e38f) ? NEGINF : fmaxf(z, LALPHA * z);
  float ls = 0.f;
  for (int it = 0; it < 128; ++it) {
    int jj = it * 64 + lane;
    unsigned long long b = mw[wv][it];
    float x = s1v + s2l[jj];
    x = fmaxf(x, LALPHA * x);
    x = ((b >> lane) & 1ull) ? x : NEGINF;
    ls += __expf(x - m);
  }
  #pragma unroll
  for (int d = 1; d < 64; d <<= 1) ls += __shfl_xor(ls, d);
  if (lane == 0) { mrow[row] = m; rlrow[row] = 1.f / ls; }
  unsigned long long* mrowg = (unsigned long long*)(outa + (size_t)row * NN);
  mrowg[lane] = mw[wv][lane];
  mrowg[lane + 64] = mw[wv][lane + 64];
}

// Kernel 3: 16 rows per block, 512 threads, 8-wave K-split (1024 cols each).
// Stages the 16 row-masks from outa into LDS (before overwriting them),
// computes exact-fp32 attention (nontemporal store) and accumulates PV via
// hi/lo bf16 MFMA. Two-stage LDS reduce of the 8 wave-partials at the end.
__global__ __launch_bounds__(512, 4) void gat_attn(
    const float* __restrict__ s1g, const float* __restrict__ s2g,
    const float* __restrict__ mrow, const float* __restrict__ rlrow,
    const unsigned short* __restrict__ whfh,
    float* __restrict__ outh, float* __restrict__ outa)
{
  __shared__ __align__(16) float s2l[NN];              // 32 KB
  __shared__ unsigned int maskl[16][258];              // 16.5 KB (stride 258: rows 2 banks apart)
  __shared__ __align__(16) float red[4][1024];         // 16 KB
  __shared__ float rowp[16][3];
  const int tid = threadIdx.x;
  const int lane = tid & 63;
  const int wv = tid >> 6;   // 0..7
  const int i0 = blockIdx.x * 16;

  #pragma unroll
  for (int it = 0; it < 4; ++it) {
    int idx = (it * 512 + tid) * 4;
    *(f32x4*)&s2l[idx] = *(const f32x4*)&s2g[idx];
  }
  #pragma unroll
  for (int i = 0; i < 8; ++i) {
    int idx = i * 512 + tid;
    int r = idx >> 8, w = idx & 255;
    maskl[r][w] = ((const unsigned int*)(outa + (size_t)(i0 + r) * NN))[w];
  }
  if (tid < 16) {
    rowp[tid][0] = s1g[i0 + tid];
    rowp[tid][1] = mrow[i0 + tid];
    rowp[tid][2] = rlrow[i0 + tid];
  }
  __syncthreads();

  const int row = lane & 15;   // A-row of the 16x16x32 fragment
  const int kg = lane >> 4;    // k-block within fragment
  const float s1r = rowp[row][0];
  const float mr = rowp[row][1];
  const float rir = rowp[row][2];
  const int kbase = wv * 1024;
  f32x4 acc0 = {0,0,0,0}, acc1 = {0,0,0,0}, acc2 = {0,0,0,0}, acc3 = {0,0,0,0};
  float* __restrict__ orow = outa + (size_t)(i0 + row) * NN;
  const short8* __restrict__ bfrag = (const short8*)whfh;
  for (int step = 0; step < 32; ++step) {
    const int k0 = kbase + step * 32;
    const int jb = k0 + kg * 8;
    f32x4 sa = *(const f32x4*)&s2l[jb];
    f32x4 sb = *(const f32x4*)&s2l[jb + 4];
    unsigned int bits = maskl[row][k0 >> 5] >> (kg * 8);
    float s2v[8] = {sa.x, sa.y, sa.z, sa.w, sb.x, sb.y, sb.z, sb.w};
    float af[8];
    short8 AH, AL;
    #pragma unroll
    for (int e = 0; e < 8; ++e) {
      float x = s1r + s2v[e];
      x = fmaxf(x, LALPHA * x);
      x = ((bits >> e) & 1u) ? x : NEGINF;
      float p = __expf(x - mr) * rir;
      af[e] = p;
      unsigned short hb = f32_to_bf16(p);
      AH[e] = (short)hb;
      AL[e] = (short)f32_to_bf16(p - bf16_to_f32(hb));
    }
    f32x4 st0 = {af[0], af[1], af[2], af[3]};
    f32x4 st1 = {af[4], af[5], af[6], af[7]};
    __builtin_nontemporal_store(st0, (f32x4*)&orow[jb]);
    __builtin_nontemporal_store(st1, (f32x4*)&orow[jb + 4]);
    size_t fb = (size_t)(k0 >> 5) * 256 + lane;  // short8 units
    short8 B0 = bfrag[fb];
    short8 B1 = bfrag[fb + 64];
    short8 B2 = bfrag[fb + 128];
    short8 B3 = bfrag[fb + 192];
    acc0 = __builtin_amdgcn_mfma_f32_16x16x32_bf16(AH, B0, acc0, 0, 0, 0);
    acc1 = __builtin_amdgcn_mfma_f32_16x16x32_bf16(AH, B1, acc1, 0, 0, 0);
    acc2 = __builtin_amdgcn_mfma_f32_16x16x32_bf16(AH, B2, acc2, 0, 0, 0);
    acc3 = __builtin_amdgcn_mfma_f32_16x16x32_bf16(AH, B3, acc3, 0, 0, 0);
    acc0 = __builtin_amdgcn_mfma_f32_16x16x32_bf16(AL, B0, acc0, 0, 0, 0);
    acc1 = __builtin_amdgcn_mfma_f32_16x16x32_bf16(AL, B1, acc1, 0, 0, 0);
    acc2 = __builtin_amdgcn_mfma_f32_16x16x32_bf16(AL, B2, acc2, 0, 0, 0);
    acc3 = __builtin_amdgcn_mfma_f32_16x16x32_bf16(AL, B3, acc3, 0, 0, 0);
  }
  // two-stage reduce of the 8 wave partials
  const int c15 = lane & 15;
  f32x4 av[4] = {acc0, acc1, acc2, acc3};
  float* myred = &red[wv & 3][0];
  if (wv < 4) {
    #pragma unroll
    for (int nt = 0; nt < 4; ++nt)
      #pragma unroll
      for (int rg = 0; rg < 4; ++rg)
        myred[(kg * 4 + rg) * 64 + nt * 16 + c15] = av[nt][rg];
  }
  __syncthreads();
  if (wv >= 4) {
    #pragma unroll
    for (int nt = 0; nt < 4; ++nt)
      #pragma unroll
      for (int rg = 0; rg < 4; ++rg)
        myred[(kg * 4 + rg) * 64 + nt * 16 + c15] += av[nt][rg];
  }
  __syncthreads();
  {
    int base = tid * 2;
    f32x2 r0 = *(f32x2*)&red[0][base];
    f32x2 r1 = *(f32x2*)&red[1][base];
    f32x2 r2 = *(f32x2*)&red[2][base];
    f32x2 r3 = *(f32x2*)&red[3][base];
    f32x2 s = r0 + r1 + r2 + r3;
    *(f32x2*)&outh[(size_t)i0 * FOUT + base] = s;
  }
}

extern "C" void kernel_launch(void* const* d_in, const int* in_sizes, int n_in,
                              void* d_out, int out_size, void* d_ws, size_t ws_size,
                              hipStream_t stream) {
  const float* h = (const float*)d_in[0];
  const int* adj = (const int*)d_in[1];
  const float* W = (const float*)d_in[2];
  const float* a = (const float*)d_in[3];
  float* outh = (float*)d_out;                    // h_prime [8192, 64]
  float* outa = outh + (size_t)NN * FOUT;         // attention [8192, 8192]
  char* ws = (char*)d_ws;                         // uses ~1.2 MB
  float* s1g = (float*)ws;
  float* s2g = s1g + NN;
  float* mrowv = s2g + NN;
  float* rlrowv = mrowv + NN;
  unsigned short* whfh = (unsigned short*)(ws + 128 * 1024);  // 1 MB B-fragments
  gat_prep<<<512, 256, 0, stream>>>(h, W, a, s1g, s2g, whfh);
  gat_mask<<<2048, 256, 0, stream>>>(adj, s1g, s2g, outa, mrowv, rlrowv);
  gat_attn<<<512, 512, 0, stream>>>(s1g, s2g, mrowv, rlrowv, whfh, outh, outa);
}

// Round 4
// 565.422 us; speedup vs baseline: 1.0328x; 1.0328x over previous
//
#include <hip/hip_runtime.h>

#define NN 8192
#define FIN 128
#define FOUT 64
#define NEGINF (-9e15f)
#define LALPHA 0.2f

typedef float f32x4 __attribute__((ext_vector_type(4)));
typedef float f32x2 __attribute__((ext_vector_type(2)));
typedef short short8 __attribute__((ext_vector_type(8)));
typedef unsigned long long ull;

__device__ __forceinline__ unsigned short f32_to_bf16(float x) {
  unsigned int u = __float_as_uint(x);
  u = (u + 0x7fffu + ((u >> 16) & 1u)) >> 16;
  return (unsigned short)u;
}
__device__ __forceinline__ float bf16_to_f32(unsigned short b) {
  return __uint_as_float(((unsigned int)b) << 16);
}

// Kernel 1 (unchanged, proven): Wh = h@W fp32, s1 = Wh@a1, s2 = Wh@a2, and Wh
// pre-swizzled into the MFMA B-fragment layout (bf16 hi) for coalesced loads.
__global__ __launch_bounds__(256) void gat_prep(
    const float* __restrict__ h, const float* __restrict__ W,
    const float* __restrict__ a,
    float* __restrict__ s1g, float* __restrict__ s2g,
    unsigned short* __restrict__ whfh)
{
  __shared__ __align__(16) float Wl[FIN * FOUT];
  __shared__ __align__(16) float hl[16 * FIN];
  const int tid = threadIdx.x;
  const int i0 = blockIdx.x * 16;
  #pragma unroll
  for (int it = 0; it < 8; ++it) {
    int idx = (it * 256 + tid) * 4;
    *(f32x4*)&Wl[idx] = *(const f32x4*)&W[idx];
  }
  #pragma unroll
  for (int it = 0; it < 2; ++it) {
    int idx = (it * 256 + tid) * 4;
    *(f32x4*)&hl[idx] = *(const f32x4*)&h[(size_t)i0 * FIN + idx];
  }
  __syncthreads();
  const int r = tid >> 4;
  const int f0 = (tid & 15) * 4;
  f32x4 acc = {0.f, 0.f, 0.f, 0.f};
  #pragma unroll 8
  for (int k = 0; k < FIN; ++k) {
    float hv = hl[r * FIN + k];
    f32x4 wv = *(const f32x4*)&Wl[k * FOUT + f0];
    acc += hv * wv;
  }
  f32x4 a1v = *(const f32x4*)&a[f0];
  f32x4 a2v = *(const f32x4*)&a[FOUT + f0];
  float p1 = acc.x * a1v.x + acc.y * a1v.y + acc.z * a1v.z + acc.w * a1v.w;
  float p2 = acc.x * a2v.x + acc.y * a2v.y + acc.z * a2v.z + acc.w * a2v.w;
  #pragma unroll
  for (int d = 1; d < 16; d <<= 1) {
    p1 += __shfl_xor(p1, d, 16);
    p2 += __shfl_xor(p2, d, 16);
  }
  const int j = i0 + r;  // row of Wh == K index of PV
  if ((tid & 15) == 0) { s1g[j] = p1; s2g[j] = p2; }
  // value Wh[k][n] -> frag[(kstep*4 + n/16)*512 + (((k%32)/8)*16 + n%16)*8 + k%8]
  const int kstep = j >> 5;
  const int lhi = (j >> 3) & 3;
  const int ein = j & 7;
  #pragma unroll
  for (int e = 0; e < 4; ++e) {
    int f = f0 + e;
    unsigned short hb = f32_to_bf16(acc[e]);
    int ln = lhi * 16 + (f & 15);
    whfh[(size_t)(kstep * 4 + (f >> 4)) * 512 + ln * 8 + ein] = hb;
  }
}

// Fused kernel: 16 rows/block, 512 threads (8 waves), 2 blocks/CU.
// P0: stage s2 into LDS + block-local global max of s2 (M_i = lrelu(s1_i+smax)
//     is a mask-independent softmax reference: common factor cancels in p/l).
// P1: ONE sweep over adj per row (2 rows/wave): ballot -> LDS bitmask, and the
//     per-lane adj value gates exp(lrelu(s1+s2)-M) into l (fused, no 2nd pass).
// P2: attention write (exact fp32, nontemporal) + hi/lo bf16 MFMA PV with
//     8-wave K-split, masks read from LDS; two-stage reduce -> h_prime.
__global__ __launch_bounds__(512, 4) void gat_fused(
    const int* __restrict__ adj,
    const float* __restrict__ s1g, const float* __restrict__ s2g,
    const unsigned short* __restrict__ whfh,
    float* __restrict__ outh, float* __restrict__ outa)
{
  __shared__ __align__(16) float s2l[NN];              // 32 KB
  __shared__ __align__(16) unsigned int maskl[16][258];// 16.5 KB (stride 258)
  __shared__ __align__(16) float red[4][1024];         // 16 KB
  __shared__ float rowp[16][3];                        // s1, M, 1/l
  __shared__ float smaxl;
  const int tid = threadIdx.x;
  const int lane = tid & 63;
  const int wv = tid >> 6;   // 0..7
  const int i0 = blockIdx.x * 16;

  // ---- P0: stage s2 + global max of s2 (block-local compute, no dependency)
  float lmax = -3.4e38f;
  #pragma unroll
  for (int it = 0; it < 4; ++it) {
    int idx = (it * 512 + tid) * 4;
    f32x4 v = *(const f32x4*)&s2g[idx];
    *(f32x4*)&s2l[idx] = v;
    lmax = fmaxf(fmaxf(fmaxf(lmax, v.x), fmaxf(v.y, v.z)), v.w);
  }
  #pragma unroll
  for (int d = 1; d < 64; d <<= 1) lmax = fmaxf(lmax, __shfl_xor(lmax, d));
  if (lane == 0) red[0][wv] = lmax;
  __syncthreads();
  if (tid == 0) {
    float m = red[0][0];
    #pragma unroll
    for (int w = 1; w < 8; ++w) m = fmaxf(m, red[0][w]);
    smaxl = m;
  }
  __syncthreads();
  const float smax = smaxl;

  // ---- P1: single adj sweep; wave wv owns rows 2wv, 2wv+1
  {
    const int r0 = wv * 2, r1 = r0 + 1;
    const float s1a = s1g[i0 + r0];
    const float s1b = s1g[i0 + r1];
    const float za = s1a + smax, zb = s1b + smax;
    const float Ma = fmaxf(za, LALPHA * za);
    const float Mb = fmaxf(zb, LALPHA * zb);
    const int* __restrict__ ara = adj + (size_t)(i0 + r0) * NN;
    const int* __restrict__ arb = adj + (size_t)(i0 + r1) * NN;
    float la = 0.f, lb = 0.f;
    #pragma unroll 4
    for (int it = 0; it < 128; ++it) {
      int jj = it * 64 + lane;
      int a0 = ara[jj];
      int a1 = arb[jj];
      float sv = s2l[jj];
      ull b0 = __ballot(a0 > 0);
      ull b1 = __ballot(a1 > 0);
      float xa = s1a + sv; xa = fmaxf(xa, LALPHA * xa);
      float xb = s1b + sv; xb = fmaxf(xb, LALPHA * xb);
      float ea = __expf(xa - Ma);
      float eb = __expf(xb - Mb);
      la += (a0 > 0) ? ea : 0.f;
      lb += (a1 > 0) ? eb : 0.f;
      if (lane == 0) {
        *(ull*)&maskl[r0][it * 2] = b0;
        *(ull*)&maskl[r1][it * 2] = b1;
      }
    }
    #pragma unroll
    for (int d = 1; d < 64; d <<= 1) {
      la += __shfl_xor(la, d);
      lb += __shfl_xor(lb, d);
    }
    if (lane == 0) {
      rowp[r0][0] = s1a; rowp[r0][1] = Ma; rowp[r0][2] = 1.f / la;
      rowp[r1][0] = s1b; rowp[r1][1] = Mb; rowp[r1][2] = 1.f / lb;
    }
  }
  __syncthreads();

  // ---- P2: attention write + MFMA PV, K split over 8 waves (1024 cols each)
  const int row = lane & 15;   // A-row of the 16x16x32 fragment
  const int kg = lane >> 4;    // k-block within fragment
  const float s1r = rowp[row][0];
  const float mr = rowp[row][1];
  const float rir = rowp[row][2];
  const int kbase = wv * 1024;
  f32x4 acc0 = {0,0,0,0}, acc1 = {0,0,0,0}, acc2 = {0,0,0,0}, acc3 = {0,0,0,0};
  float* __restrict__ orow = outa + (size_t)(i0 + row) * NN;
  const short8* __restrict__ bfrag = (const short8*)whfh;
  for (int step = 0; step < 32; ++step) {
    const int k0 = kbase + step * 32;
    const int jb = k0 + kg * 8;
    f32x4 sa = *(const f32x4*)&s2l[jb];
    f32x4 sb = *(const f32x4*)&s2l[jb + 4];
    unsigned int bits = maskl[row][k0 >> 5] >> (kg * 8);
    float s2v[8] = {sa.x, sa.y, sa.z, sa.w, sb.x, sb.y, sb.z, sb.w};
    float af[8];
    short8 AH, AL;
    #pragma unroll
    for (int e = 0; e < 8; ++e) {
      float x = s1r + s2v[e];
      x = fmaxf(x, LALPHA * x);
      x = ((bits >> e) & 1u) ? x : NEGINF;
      float p = __expf(x - mr) * rir;
      af[e] = p;
      unsigned short hb = f32_to_bf16(p);
      AH[e] = (short)hb;
      AL[e] = (short)f32_to_bf16(p - bf16_to_f32(hb));
    }
    f32x4 st0 = {af[0], af[1], af[2], af[3]};
    f32x4 st1 = {af[4], af[5], af[6], af[7]};
    __builtin_nontemporal_store(st0, (f32x4*)&orow[jb]);
    __builtin_nontemporal_store(st1, (f32x4*)&orow[jb + 4]);
    size_t fb = (size_t)(k0 >> 5) * 256 + lane;  // short8 units
    short8 B0 = bfrag[fb];
    short8 B1 = bfrag[fb + 64];
    short8 B2 = bfrag[fb + 128];
    short8 B3 = bfrag[fb + 192];
    acc0 = __builtin_amdgcn_mfma_f32_16x16x32_bf16(AH, B0, acc0, 0, 0, 0);
    acc1 = __builtin_amdgcn_mfma_f32_16x16x32_bf16(AH, B1, acc1, 0, 0, 0);
    acc2 = __builtin_amdgcn_mfma_f32_16x16x32_bf16(AH, B2, acc2, 0, 0, 0);
    acc3 = __builtin_amdgcn_mfma_f32_16x16x32_bf16(AH, B3, acc3, 0, 0, 0);
    acc0 = __builtin_amdgcn_mfma_f32_16x16x32_bf16(AL, B0, acc0, 0, 0, 0);
    acc1 = __builtin_amdgcn_mfma_f32_16x16x32_bf16(AL, B1, acc1, 0, 0, 0);
    acc2 = __builtin_amdgcn_mfma_f32_16x16x32_bf16(AL, B2, acc2, 0, 0, 0);
    acc3 = __builtin_amdgcn_mfma_f32_16x16x32_bf16(AL, B3, acc3, 0, 0, 0);
  }
  // two-stage reduce of the 8 wave partials
  const int c15 = lane & 15;
  f32x4 av[4] = {acc0, acc1, acc2, acc3};
  float* myred = &red[wv & 3][0];
  __syncthreads();  // red[0] was used for smax scratch; also fence maskl reads
  if (wv < 4) {
    #pragma unroll
    for (int nt = 0; nt < 4; ++nt)
      #pragma unroll
      for (int rg = 0; rg < 4; ++rg)
        myred[(kg * 4 + rg) * 64 + nt * 16 + c15] = av[nt][rg];
  }
  __syncthreads();
  if (wv >= 4) {
    #pragma unroll
    for (int nt = 0; nt < 4; ++nt)
      #pragma unroll
      for (int rg = 0; rg < 4; ++rg)
        myred[(kg * 4 + rg) * 64 + nt * 16 + c15] += av[nt][rg];
  }
  __syncthreads();
  {
    int base = tid * 2;
    f32x2 r0 = *(f32x2*)&red[0][base];
    f32x2 r1 = *(f32x2*)&red[1][base];
    f32x2 r2 = *(f32x2*)&red[2][base];
    f32x2 r3 = *(f32x2*)&red[3][base];
    f32x2 s = r0 + r1 + r2 + r3;
    *(f32x2*)&outh[(size_t)i0 * FOUT + base] = s;
  }
}

extern "C" void kernel_launch(void* const* d_in, const int* in_sizes, int n_in,
                              void* d_out, int out_size, void* d_ws, size_t ws_size,
                              hipStream_t stream) {
  const float* h = (const float*)d_in[0];
  const int* adj = (const int*)d_in[1];
  const float* W = (const float*)d_in[2];
  const float* a = (const float*)d_in[3];
  float* outh = (float*)d_out;                    // h_prime [8192, 64]
  float* outa = outh + (size_t)NN * FOUT;         // attention [8192, 8192]
  char* ws = (char*)d_ws;                         // uses ~1.2 MB
  float* s1g = (float*)ws;
  float* s2g = s1g + NN;
  unsigned short* whfh = (unsigned short*)(ws + 128 * 1024);  // 1 MB B-fragments
  gat_prep<<<512, 256, 0, stream>>>(h, W, a, s1g, s2g, whfh);
  gat_fused<<<512, 512, 0, stream>>>(adj, s1g, s2g, whfh, outh, outa);
}

// Round 6
// 511.988 us; speedup vs baseline: 1.1406x; 1.1044x over previous
//
#include <hip/hip_runtime.h>

#define NN 8192
#define FIN 128
#define FOUT 64
#define NEGINF (-9e15f)
#define LALPHA 0.2f

typedef float f32x4 __attribute__((ext_vector_type(4)));
typedef float f32x2 __attribute__((ext_vector_type(2)));
typedef short short8 __attribute__((ext_vector_type(8)));
typedef unsigned long long ull;

__device__ __forceinline__ unsigned short f32_to_bf16(float x) {
  unsigned int u = __float_as_uint(x);
  u = (u + 0x7fffu + ((u >> 16) & 1u)) >> 16;
  return (unsigned short)u;
}
__device__ __forceinline__ float bf16_to_f32(unsigned short b) {
  return __uint_as_float(((unsigned int)b) << 16);
}

// Kernel 1 (unchanged, proven): Wh = h@W fp32, s1 = Wh@a1, s2 = Wh@a2, and Wh
// pre-swizzled into the MFMA B-fragment layout (bf16 hi) for coalesced loads.
__global__ __launch_bounds__(256) void gat_prep(
    const float* __restrict__ h, const float* __restrict__ W,
    const float* __restrict__ a,
    float* __restrict__ s1g, float* __restrict__ s2g,
    unsigned short* __restrict__ whfh)
{
  __shared__ __align__(16) float Wl[FIN * FOUT];
  __shared__ __align__(16) float hl[16 * FIN];
  const int tid = threadIdx.x;
  const int i0 = blockIdx.x * 16;
  #pragma unroll
  for (int it = 0; it < 8; ++it) {
    int idx = (it * 256 + tid) * 4;
    *(f32x4*)&Wl[idx] = *(const f32x4*)&W[idx];
  }
  #pragma unroll
  for (int it = 0; it < 2; ++it) {
    int idx = (it * 256 + tid) * 4;
    *(f32x4*)&hl[idx] = *(const f32x4*)&h[(size_t)i0 * FIN + idx];
  }
  __syncthreads();
  const int r = tid >> 4;
  const int f0 = (tid & 15) * 4;
  f32x4 acc = {0.f, 0.f, 0.f, 0.f};
  #pragma unroll 8
  for (int k = 0; k < FIN; ++k) {
    float hv = hl[r * FIN + k];
    f32x4 wv = *(const f32x4*)&Wl[k * FOUT + f0];
    acc += hv * wv;
  }
  f32x4 a1v = *(const f32x4*)&a[f0];
  f32x4 a2v = *(const f32x4*)&a[FOUT + f0];
  float p1 = acc.x * a1v.x + acc.y * a1v.y + acc.z * a1v.z + acc.w * a1v.w;
  float p2 = acc.x * a2v.x + acc.y * a2v.y + acc.z * a2v.z + acc.w * a2v.w;
  #pragma unroll
  for (int d = 1; d < 16; d <<= 1) {
    p1 += __shfl_xor(p1, d, 16);
    p2 += __shfl_xor(p2, d, 16);
  }
  const int j = i0 + r;  // row of Wh == K index of PV
  if ((tid & 15) == 0) { s1g[j] = p1; s2g[j] = p2; }
  // value Wh[k][n] -> frag[(kstep*4 + n/16)*512 + (((k%32)/8)*16 + n%16)*8 + k%8]
  const int kstep = j >> 5;
  const int lhi = (j >> 3) & 3;
  const int ein = j & 7;
  #pragma unroll
  for (int e = 0; e < 4; ++e) {
    int f = f0 + e;
    unsigned short hb = f32_to_bf16(acc[e]);
    int ln = lhi * 16 + (f & 15);
    whfh[(size_t)(kstep * 4 + (f >> 4)) * 512 + ln * 8 + ein] = hb;
  }
}

// Fused kernel. Changes vs round 4 (one theory: the attention-store path):
//  - attention stores are PLAIN cached stores (L2 merges the 16B-scatter into
//    full lines; NT was causing partial-line RMW at HBM -> WRITE 318MB vs 256)
//  - adj loads are NONTEMPORAL (keep 256MB read stream from thrashing the L2
//    the stores + bfrag now rely on)
__global__ __launch_bounds__(512, 4) void gat_fused(
    const int* __restrict__ adj,
    const float* __restrict__ s1g, const float* __restrict__ s2g,
    const unsigned short* __restrict__ whfh,
    float* __restrict__ outh, float* __restrict__ outa)
{
  __shared__ __align__(16) float s2l[NN];              // 32 KB
  __shared__ __align__(16) unsigned int maskl[16][258];// 16.5 KB (stride 258)
  __shared__ __align__(16) float red[4][1024];         // 16 KB
  __shared__ float rowp[16][3];                        // s1, M, 1/l
  __shared__ float smaxl;
  const int tid = threadIdx.x;
  const int lane = tid & 63;
  const int wv = tid >> 6;   // 0..7
  const int i0 = blockIdx.x * 16;

  // ---- P0: stage s2 + global max of s2 (block-local, mask-independent M)
  float lmax = -3.4e38f;
  #pragma unroll
  for (int it = 0; it < 4; ++it) {
    int idx = (it * 512 + tid) * 4;
    f32x4 v = *(const f32x4*)&s2g[idx];
    *(f32x4*)&s2l[idx] = v;
    lmax = fmaxf(fmaxf(fmaxf(lmax, v.x), fmaxf(v.y, v.z)), v.w);
  }
  #pragma unroll
  for (int d = 1; d < 64; d <<= 1) lmax = fmaxf(lmax, __shfl_xor(lmax, d));
  if (lane == 0) red[0][wv] = lmax;
  __syncthreads();
  if (tid == 0) {
    float m = red[0][0];
    #pragma unroll
    for (int w = 1; w < 8; ++w) m = fmaxf(m, red[0][w]);
    smaxl = m;
  }
  __syncthreads();
  const float smax = smaxl;

  // ---- P1: single adj sweep; wave wv owns rows 2wv, 2wv+1
  {
    const int r0 = wv * 2, r1 = r0 + 1;
    const float s1a = s1g[i0 + r0];
    const float s1b = s1g[i0 + r1];
    const float za = s1a + smax, zb = s1b + smax;
    const float Ma = fmaxf(za, LALPHA * za);
    const float Mb = fmaxf(zb, LALPHA * zb);
    const int* __restrict__ ara = adj + (size_t)(i0 + r0) * NN;
    const int* __restrict__ arb = adj + (size_t)(i0 + r1) * NN;
    float la = 0.f, lb = 0.f;
    #pragma unroll 4
    for (int it = 0; it < 128; ++it) {
      int jj = it * 64 + lane;
      int a0 = __builtin_nontemporal_load(&ara[jj]);
      int a1 = __builtin_nontemporal_load(&arb[jj]);
      float sv = s2l[jj];
      ull b0 = __ballot(a0 > 0);
      ull b1 = __ballot(a1 > 0);
      float xa = s1a + sv; xa = fmaxf(xa, LALPHA * xa);
      float xb = s1b + sv; xb = fmaxf(xb, LALPHA * xb);
      float ea = __expf(xa - Ma);
      float eb = __expf(xb - Mb);
      la += (a0 > 0) ? ea : 0.f;
      lb += (a1 > 0) ? eb : 0.f;
      if (lane == 0) {
        *(ull*)&maskl[r0][it * 2] = b0;
        *(ull*)&maskl[r1][it * 2] = b1;
      }
    }
    #pragma unroll
    for (int d = 1; d < 64; d <<= 1) {
      la += __shfl_xor(la, d);
      lb += __shfl_xor(lb, d);
    }
    if (lane == 0) {
      rowp[r0][0] = s1a; rowp[r0][1] = Ma; rowp[r0][2] = 1.f / la;
      rowp[r1][0] = s1b; rowp[r1][1] = Mb; rowp[r1][2] = 1.f / lb;
    }
  }
  __syncthreads();

  // ---- P2: attention write + MFMA PV, K split over 8 waves (1024 cols each)
  const int row = lane & 15;   // A-row of the 16x16x32 fragment
  const int kg = lane >> 4;    // k-block within fragment
  const float s1r = rowp[row][0];
  const float mr = rowp[row][1];
  const float rir = rowp[row][2];
  const int kbase = wv * 1024;
  f32x4 acc0 = {0,0,0,0}, acc1 = {0,0,0,0}, acc2 = {0,0,0,0}, acc3 = {0,0,0,0};
  float* __restrict__ orow = outa + (size_t)(i0 + row) * NN;
  const short8* __restrict__ bfrag = (const short8*)whfh;
  for (int step = 0; step < 32; ++step) {
    const int k0 = kbase + step * 32;
    const int jb = k0 + kg * 8;
    f32x4 sa = *(const f32x4*)&s2l[jb];
    f32x4 sb = *(const f32x4*)&s2l[jb + 4];
    unsigned int bits = maskl[row][k0 >> 5] >> (kg * 8);
    float s2v[8] = {sa.x, sa.y, sa.z, sa.w, sb.x, sb.y, sb.z, sb.w};
    float af[8];
    short8 AH, AL;
    #pragma unroll
    for (int e = 0; e < 8; ++e) {
      float x = s1r + s2v[e];
      x = fmaxf(x, LALPHA * x);
      x = ((bits >> e) & 1u) ? x : NEGINF;
      float p = __expf(x - mr) * rir;
      af[e] = p;
      unsigned short hb = f32_to_bf16(p);
      AH[e] = (short)hb;
      AL[e] = (short)f32_to_bf16(p - bf16_to_f32(hb));
    }
    f32x4 st0 = {af[0], af[1], af[2], af[3]};
    f32x4 st1 = {af[4], af[5], af[6], af[7]};
    *(f32x4*)&orow[jb] = st0;        // plain cached store: L2 merges lines
    *(f32x4*)&orow[jb + 4] = st1;
    size_t fb = (size_t)(k0 >> 5) * 256 + lane;  // short8 units
    short8 B0 = bfrag[fb];
    short8 B1 = bfrag[fb + 64];
    short8 B2 = bfrag[fb + 128];
    short8 B3 = bfrag[fb + 192];
    acc0 = __builtin_amdgcn_mfma_f32_16x16x32_bf16(AH, B0, acc0, 0, 0, 0);
    acc1 = __builtin_amdgcn_mfma_f32_16x16x32_bf16(AH, B1, acc1, 0, 0, 0);
    acc2 = __builtin_amdgcn_mfma_f32_16x16x32_bf16(AH, B2, acc2, 0, 0, 0);
    acc3 = __builtin_amdgcn_mfma_f32_16x16x32_bf16(AH, B3, acc3, 0, 0, 0);
    acc0 = __builtin_amdgcn_mfma_f32_16x16x32_bf16(AL, B0, acc0, 0, 0, 0);
    acc1 = __builtin_amdgcn_mfma_f32_16x16x32_bf16(AL, B1, acc1, 0, 0, 0);
    acc2 = __builtin_amdgcn_mfma_f32_16x16x32_bf16(AL, B2, acc2, 0, 0, 0);
    acc3 = __builtin_amdgcn_mfma_f32_16x16x32_bf16(AL, B3, acc3, 0, 0, 0);
  }
  // two-stage reduce of the 8 wave partials
  const int c15 = lane & 15;
  f32x4 av[4] = {acc0, acc1, acc2, acc3};
  float* myred = &red[wv & 3][0];
  __syncthreads();  // red[0] was smax scratch; also fence maskl reads
  if (wv < 4) {
    #pragma unroll
    for (int nt = 0; nt < 4; ++nt)
      #pragma unroll
      for (int rg = 0; rg < 4; ++rg)
        myred[(kg * 4 + rg) * 64 + nt * 16 + c15] = av[nt][rg];
  }
  __syncthreads();
  if (wv >= 4) {
    #pragma unroll
    for (int nt = 0; nt < 4; ++nt)
      #pragma unroll
      for (int rg = 0; rg < 4; ++rg)
        myred[(kg * 4 + rg) * 64 + nt * 16 + c15] += av[nt][rg];
  }
  __syncthreads();
  {
    int base = tid * 2;
    f32x2 r0 = *(f32x2*)&red[0][base];
    f32x2 r1 = *(f32x2*)&red[1][base];
    f32x2 r2 = *(f32x2*)&red[2][base];
    f32x2 r3 = *(f32x2*)&red[3][base];
    f32x2 s = r0 + r1 + r2 + r3;
    *(f32x2*)&outh[(size_t)i0 * FOUT + base] = s;
  }
}

extern "C" void kernel_launch(void* const* d_in, const int* in_sizes, int n_in,
                              void* d_out, int out_size, void* d_ws, size_t ws_size,
                              hipStream_t stream) {
  const float* h = (const float*)d_in[0];
  const int* adj = (const int*)d_in[1];
  const float* W = (const float*)d_in[2];
  const float* a = (const float*)d_in[3];
  float* outh = (float*)d_out;                    // h_prime [8192, 64]
  float* outa = outh + (size_t)NN * FOUT;         // attention [8192, 8192]
  char* ws = (char*)d_ws;                         // uses ~1.2 MB
  float* s1g = (float*)ws;
  float* s2g = s1g + NN;
  unsigned short* whfh = (unsigned short*)(ws + 128 * 1024);  // 1 MB B-fragments
  gat_prep<<<512, 256, 0, stream>>>(h, W, a, s1g, s2g, whfh);
  gat_fused<<<512, 512, 0, stream>>>(adj, s1g, s2g, whfh, outh, outa);
}

// Round 7
// 507.013 us; speedup vs baseline: 1.1518x; 1.0098x over previous
//
#include <hip/hip_runtime.h>

#define NN 8192
#define FIN 128
#define FOUT 64
#define NEGINF (-9e15f)
#define LALPHA 0.2f

typedef float f32x4 __attribute__((ext_vector_type(4)));
typedef short short8 __attribute__((ext_vector_type(8)));
typedef unsigned long long ull;

__device__ __forceinline__ unsigned short f32_to_bf16(float x) {
  unsigned int u = __float_as_uint(x);
  u = (u + 0x7fffu + ((u >> 16) & 1u)) >> 16;
  return (unsigned short)u;
}
__device__ __forceinline__ float bf16_to_f32(unsigned short b) {
  return __uint_as_float(((unsigned int)b) << 16);
}

// Kernel 1 (unchanged, proven): Wh = h@W fp32, s1 = Wh@a1, s2 = Wh@a2, and Wh
// pre-swizzled into the MFMA B-fragment layout (bf16 hi) for coalesced loads.
__global__ __launch_bounds__(256) void gat_prep(
    const float* __restrict__ h, const float* __restrict__ W,
    const float* __restrict__ a,
    float* __restrict__ s1g, float* __restrict__ s2g,
    unsigned short* __restrict__ whfh)
{
  __shared__ __align__(16) float Wl[FIN * FOUT];
  __shared__ __align__(16) float hl[16 * FIN];
  const int tid = threadIdx.x;
  const int i0 = blockIdx.x * 16;
  #pragma unroll
  for (int it = 0; it < 8; ++it) {
    int idx = (it * 256 + tid) * 4;
    *(f32x4*)&Wl[idx] = *(const f32x4*)&W[idx];
  }
  #pragma unroll
  for (int it = 0; it < 2; ++it) {
    int idx = (it * 256 + tid) * 4;
    *(f32x4*)&hl[idx] = *(const f32x4*)&h[(size_t)i0 * FIN + idx];
  }
  __syncthreads();
  const int r = tid >> 4;
  const int f0 = (tid & 15) * 4;
  f32x4 acc = {0.f, 0.f, 0.f, 0.f};
  #pragma unroll 8
  for (int k = 0; k < FIN; ++k) {
    float hv = hl[r * FIN + k];
    f32x4 wv = *(const f32x4*)&Wl[k * FOUT + f0];
    acc += hv * wv;
  }
  f32x4 a1v = *(const f32x4*)&a[f0];
  f32x4 a2v = *(const f32x4*)&a[FOUT + f0];
  float p1 = acc.x * a1v.x + acc.y * a1v.y + acc.z * a1v.z + acc.w * a1v.w;
  float p2 = acc.x * a2v.x + acc.y * a2v.y + acc.z * a2v.z + acc.w * a2v.w;
  #pragma unroll
  for (int d = 1; d < 16; d <<= 1) {
    p1 += __shfl_xor(p1, d, 16);
    p2 += __shfl_xor(p2, d, 16);
  }
  const int j = i0 + r;  // row of Wh == K index of PV
  if ((tid & 15) == 0) { s1g[j] = p1; s2g[j] = p2; }
  // value Wh[k][n] -> frag[(kstep*4 + n/16)*512 + (((k%32)/8)*16 + n%16)*8 + k%8]
  const int kstep = j >> 5;
  const int lhi = (j >> 3) & 3;
  const int ein = j & 7;
  #pragma unroll
  for (int e = 0; e < 4; ++e) {
    int f = f0 + e;
    unsigned short hb = f32_to_bf16(acc[e]);
    int ln = lhi * 16 + (f & 15);
    whfh[(size_t)(kstep * 4 + (f >> 4)) * 512 + ln * 8 + ein] = hb;
  }
}

// Fused kernel, 1024 threads (16 waves), 2 blocks/CU -> 32 waves/CU (100%).
// Changes vs round 6 (one theory: grid-limited parallelism / phase mixing):
//  - 1024-thread blocks: P1 = 1 row/wave, P2 = 16-way K-split (512 cols/wave)
//  - P0 smax phase REMOVED: M_r = lrelu(s1_r) is row-consistent between l and
//    p (reference point cancels algebraically; |x-M| <= ~|s2| so no overflow)
//  - reduce buffer aliased onto maskl (dead after PV loop) -> LDS 49.5 KB
__global__ __launch_bounds__(1024, 8) void gat_fused(
    const int* __restrict__ adj,
    const float* __restrict__ s1g, const float* __restrict__ s2g,
    const unsigned short* __restrict__ whfh,
    float* __restrict__ outh, float* __restrict__ outa)
{
  __shared__ __align__(16) float s2l[NN];               // 32 KB
  __shared__ __align__(16) unsigned int maskl[16][258]; // 16.5 KB; red aliases
  __shared__ float rowp[16][3];                         // s1, M, 1/l
  const int tid = threadIdx.x;
  const int lane = tid & 63;
  const int wv = tid >> 6;   // 0..15
  const int i0 = blockIdx.x * 16;

  // ---- P0: stage s2 into LDS
  #pragma unroll
  for (int it = 0; it < 2; ++it) {
    int idx = (it * 1024 + tid) * 4;
    *(f32x4*)&s2l[idx] = *(const f32x4*)&s2g[idx];
  }
  __syncthreads();

  // ---- P1: wave wv sweeps row i0+wv: ballot mask + fused gated-exp l
  {
    const float s1v = s1g[i0 + wv];
    const float M = fmaxf(s1v, LALPHA * s1v);  // lrelu(s1): row-local reference
    const int* __restrict__ ar = adj + (size_t)(i0 + wv) * NN;
    float ls = 0.f;
    #pragma unroll 4
    for (int it = 0; it < 128; ++it) {
      int jj = it * 64 + lane;
      int a0 = __builtin_nontemporal_load(&ar[jj]);
      float sv = s2l[jj];
      ull b = __ballot(a0 > 0);
      float x = s1v + sv;
      x = fmaxf(x, LALPHA * x);
      float e = __expf(x - M);
      ls += (a0 > 0) ? e : 0.f;
      if (lane == 0) *(ull*)&maskl[wv][it * 2] = b;
    }
    #pragma unroll
    for (int d = 1; d < 64; d <<= 1) ls += __shfl_xor(ls, d);
    if (lane == 0) {
      rowp[wv][0] = s1v; rowp[wv][1] = M; rowp[wv][2] = 1.f / ls;
    }
  }
  __syncthreads();

  // ---- P2: attention write + MFMA PV, K split over 16 waves (512 cols each)
  const int row = lane & 15;   // A-row of the 16x16x32 fragment
  const int kg = lane >> 4;    // k-block within fragment
  const float s1r = rowp[row][0];
  const float mr = rowp[row][1];
  const float rir = rowp[row][2];
  const int kbase = wv * 512;
  f32x4 acc0 = {0,0,0,0}, acc1 = {0,0,0,0}, acc2 = {0,0,0,0}, acc3 = {0,0,0,0};
  float* __restrict__ orow = outa + (size_t)(i0 + row) * NN;
  const short8* __restrict__ bfrag = (const short8*)whfh;
  for (int step = 0; step < 16; ++step) {
    const int k0 = kbase + step * 32;
    const int jb = k0 + kg * 8;
    f32x4 sa = *(const f32x4*)&s2l[jb];
    f32x4 sb = *(const f32x4*)&s2l[jb + 4];
    unsigned int bits = maskl[row][k0 >> 5] >> (kg * 8);
    float s2v[8] = {sa.x, sa.y, sa.z, sa.w, sb.x, sb.y, sb.z, sb.w};
    float af[8];
    short8 AH, AL;
    #pragma unroll
    for (int e = 0; e < 8; ++e) {
      float x = s1r + s2v[e];
      x = fmaxf(x, LALPHA * x);
      x = ((bits >> e) & 1u) ? x : NEGINF;
      float p = __expf(x - mr) * rir;
      af[e] = p;
      unsigned short hb = f32_to_bf16(p);
      AH[e] = (short)hb;
      AL[e] = (short)f32_to_bf16(p - bf16_to_f32(hb));
    }
    f32x4 st0 = {af[0], af[1], af[2], af[3]};
    f32x4 st1 = {af[4], af[5], af[6], af[7]};
    *(f32x4*)&orow[jb] = st0;        // plain cached store: L2 merges lines
    *(f32x4*)&orow[jb + 4] = st1;
    size_t fb = (size_t)(k0 >> 5) * 256 + lane;  // short8 units
    short8 B0 = bfrag[fb];
    short8 B1 = bfrag[fb + 64];
    short8 B2 = bfrag[fb + 128];
    short8 B3 = bfrag[fb + 192];
    acc0 = __builtin_amdgcn_mfma_f32_16x16x32_bf16(AH, B0, acc0, 0, 0, 0);
    acc1 = __builtin_amdgcn_mfma_f32_16x16x32_bf16(AH, B1, acc1, 0, 0, 0);
    acc2 = __builtin_amdgcn_mfma_f32_16x16x32_bf16(AH, B2, acc2, 0, 0, 0);
    acc3 = __builtin_amdgcn_mfma_f32_16x16x32_bf16(AH, B3, acc3, 0, 0, 0);
    acc0 = __builtin_amdgcn_mfma_f32_16x16x32_bf16(AL, B0, acc0, 0, 0, 0);
    acc1 = __builtin_amdgcn_mfma_f32_16x16x32_bf16(AL, B1, acc1, 0, 0, 0);
    acc2 = __builtin_amdgcn_mfma_f32_16x16x32_bf16(AL, B2, acc2, 0, 0, 0);
    acc3 = __builtin_amdgcn_mfma_f32_16x16x32_bf16(AL, B3, acc3, 0, 0, 0);
  }
  // 4-stage reduce of the 16 wave partials; red aliases maskl (dead now)
  __syncthreads();  // ALL waves done reading maskl before overwrite
  float* red = (float*)&maskl[0][0];  // 16 KB region
  const int c15 = lane & 15;
  f32x4 av[4] = {acc0, acc1, acc2, acc3};
  float* slab = red + (wv & 3) * 1024;
  if (wv < 4) {
    #pragma unroll
    for (int nt = 0; nt < 4; ++nt)
      #pragma unroll
      for (int rg = 0; rg < 4; ++rg)
        slab[(kg * 4 + rg) * 64 + nt * 16 + c15] = av[nt][rg];
  }
  __syncthreads();
  if (wv >= 4 && wv < 8) {
    #pragma unroll
    for (int nt = 0; nt < 4; ++nt)
      #pragma unroll
      for (int rg = 0; rg < 4; ++rg)
        slab[(kg * 4 + rg) * 64 + nt * 16 + c15] += av[nt][rg];
  }
  __syncthreads();
  if (wv >= 8 && wv < 12) {
    #pragma unroll
    for (int nt = 0; nt < 4; ++nt)
      #pragma unroll
      for (int rg = 0; rg < 4; ++rg)
        slab[(kg * 4 + rg) * 64 + nt * 16 + c15] += av[nt][rg];
  }
  __syncthreads();
  if (wv >= 12) {
    #pragma unroll
    for (int nt = 0; nt < 4; ++nt)
      #pragma unroll
      for (int rg = 0; rg < 4; ++rg)
        slab[(kg * 4 + rg) * 64 + nt * 16 + c15] += av[nt][rg];
  }
  __syncthreads();
  outh[(size_t)i0 * FOUT + tid] =
      red[tid] + red[1024 + tid] + red[2048 + tid] + red[3072 + tid];
}

extern "C" void kernel_launch(void* const* d_in, const int* in_sizes, int n_in,
                              void* d_out, int out_size, void* d_ws, size_t ws_size,
                              hipStream_t stream) {
  const float* h = (const float*)d_in[0];
  const int* adj = (const int*)d_in[1];
  const float* W = (const float*)d_in[2];
  const float* a = (const float*)d_in[3];
  float* outh = (float*)d_out;                    // h_prime [8192, 64]
  float* outa = outh + (size_t)NN * FOUT;         // attention [8192, 8192]
  char* ws = (char*)d_ws;                         // uses ~1.2 MB
  float* s1g = (float*)ws;
  float* s2g = s1g + NN;
  unsigned short* whfh = (unsigned short*)(ws + 128 * 1024);  // 1 MB B-fragments
  gat_prep<<<512, 256, 0, stream>>>(h, W, a, s1g, s2g, whfh);
  gat_fused<<<512, 1024, 0, stream>>>(adj, s1g, s2g, whfh, outh, outa);
}